// Round 1
// baseline (1562.349 us; speedup 1.0000x reference)
//
#include <hip/hip_runtime.h>
#include <hip/hip_bf16.h>

// HEALPixTransformer: B=2, N=3072, C=4, P=4 -> Nt=768, E=512, H=8, hd=64, T=256, F=64, L=4
// Round 1: full fp32 implementation, correctness-first. Generic tiled GEMM reused for
// qkv / out / mlp1 / mlp2 / QK^T(+bias epi) / PV. Bias table computed once, reused x4 layers.
// Workspace use ~106 MB.

#define NT 768
#define EDIM 512
#define E3 1536
#define E4 2048
#define HD 64
#define NH 8
#define TB 2   // batch

// ---------------- vnorm: v = normalize(mean_p(vec_map)) ----------------
__global__ __launch_bounds__(256) void k_vnorm(const float* __restrict__ vm, float* __restrict__ v) {
    int idx = blockIdx.x * 256 + threadIdx.x;           // b*Nt + nt
    if (idx >= TB * NT) return;
    float s0 = 0.f, s1 = 0.f, s2 = 0.f;
    #pragma unroll
    for (int p = 0; p < 4; ++p) {
        s0 += vm[(idx * 4 + p) * 3 + 0];
        s1 += vm[(idx * 4 + p) * 3 + 1];
        s2 += vm[(idx * 4 + p) * 3 + 2];
    }
    s0 *= 0.25f; s1 *= 0.25f; s2 *= 0.25f;
    float inv = 1.f / sqrtf(s0 * s0 + s1 * s1 + s2 * s2);
    v[idx * 3 + 0] = s0 * inv; v[idx * 3 + 1] = s1 * inv; v[idx * 3 + 2] = s2 * inv;
}

// ---------------- bias table: biasT[b][h][q][k]  (B,H,Nt,Nt) ----------------
__global__ __launch_bounds__(256) void k_bias(const float* __restrict__ v, const float* __restrict__ W_rb,
                                              const float* __restrict__ b_rb, float* __restrict__ biasT) {
    int bq = blockIdx.x; int b = bq / NT, q = bq % NT;
    __shared__ float sv[NT * 3];
    __shared__ float sw[64 * 8];
    __shared__ float sb[NT * 8];
    int tid = threadIdx.x;
    for (int i = tid; i < NT * 3; i += 256) sv[i] = v[b * NT * 3 + i];
    for (int i = tid; i < 512; i += 256) sw[i] = W_rb[i];
    __syncthreads();
    float vq0 = sv[q * 3], vq1 = sv[q * 3 + 1], vq2 = sv[q * 3 + 2];
    float br[8];
    #pragma unroll
    for (int h = 0; h < 8; ++h) br[h] = b_rb[h];
    for (int k = tid; k < NT; k += 256) {
        float d0 = vq0 - sv[k * 3], d1 = vq1 - sv[k * 3 + 1], d2 = vq2 - sv[k * 3 + 2];
        float dot = 1.f - 0.5f * (d0 * d0 + d1 * d1 + d2 * d2);
        dot = fminf(1.f, fmaxf(-1.f, dot));
        float angle = acosf(dot) * 200.f;   // /0.005
        float acc[8];
        #pragma unroll
        for (int h = 0; h < 8; ++h) acc[h] = br[h];
        #pragma unroll
        for (int f = 0; f < 32; ++f) {
            float sn, cs;
            __sincosf((10.f / 31.f) * (float)f * angle, &sn, &cs);
            #pragma unroll
            for (int h = 0; h < 8; ++h) acc[h] += sn * sw[f * 8 + h] + cs * sw[(f + 32) * 8 + h];
        }
        #pragma unroll
        for (int h = 0; h < 8; ++h) sb[k * 8 + h] = acc[h];
    }
    __syncthreads();
    long base = (long)b * NH * NT * NT + (long)q * NT;
    for (int h = 0; h < 8; ++h)
        for (int k = tid; k < NT; k += 256)
            biasT[base + (long)h * NT * NT + k] = sb[k * 8 + h];
}

// ---------------- embed: h0 = xp @ W_embed + b_embed + pos_emb ----------------
__global__ __launch_bounds__(256) void k_embed(const float* __restrict__ x, const float* __restrict__ W,
                                               const float* __restrict__ be, const float* __restrict__ pe,
                                               float* __restrict__ xc) {
    int row = blockIdx.x; int nt = row % NT;
    __shared__ float sx[16];
    int tid = threadIdx.x;
    if (tid < 16) sx[tid] = x[row * 16 + tid];
    __syncthreads();
    for (int e = tid; e < EDIM; e += 256) {
        float a = be[e] + pe[nt * EDIM + e];
        #pragma unroll
        for (int j = 0; j < 16; ++j) a += sx[j] * W[j * EDIM + e];
        xc[(long)row * EDIM + e] = a;
    }
}

// ---------------- adaLN precompute (all L, both halves): ada[(l*2+w)*2+b][1536] ----------------
__global__ __launch_bounds__(256) void k_adaln(const float* __restrict__ t,
    const float* __restrict__ a1W1, const float* __restrict__ a1b1, const float* __restrict__ a1W2, const float* __restrict__ a1b2,
    const float* __restrict__ a2W1, const float* __restrict__ a2b1, const float* __restrict__ a2W2, const float* __restrict__ a2b2,
    float* __restrict__ ada) {
    int blk = blockIdx.x; int b = blk & 1, lw = blk >> 1; int which = lw & 1, l = lw >> 1;
    const float* W1 = (which ? a2W1 : a1W1) + (long)l * 256 * 256;
    const float* b1 = (which ? a2b1 : a1b1) + l * 256;
    const float* W2 = (which ? a2W2 : a1W2) + (long)l * 256 * E3;
    const float* b2 = (which ? a2b2 : a1b2) + l * E3;
    __shared__ float st[256], sh[256];
    int tid = threadIdx.x;
    st[tid] = t[b * 256 + tid];
    __syncthreads();
    float a = b1[tid];
    for (int i = 0; i < 256; ++i) a += st[i] * W1[i * 256 + tid];
    sh[tid] = a / (1.f + __expf(-a));    // silu
    __syncthreads();
    float* outp = ada + (long)(lw * 2 + b) * E3;
    for (int c = tid; c < E3; c += 256) {
        float m = b2[c];
        for (int i = 0; i < 256; ++i) m += sh[i] * W2[i * E3 + c];
        outp[c] = m;
    }
}

// ---------------- LN + modulate: out = (g+1)*LN(xc) + be ----------------
__global__ __launch_bounds__(256) void k_lnmod(const float* __restrict__ xc, const float* __restrict__ ada,
                                               float* __restrict__ out, int lw) {
    int row = blockIdx.x; int b = row / NT;
    const float* ap = ada + (long)(lw * 2 + b) * E3;
    int tid = threadIdx.x;
    float2 vv = *(const float2*)(xc + (long)row * EDIM + tid * 2);
    float s1 = vv.x + vv.y, s2 = vv.x * vv.x + vv.y * vv.y;
    for (int o = 32; o; o >>= 1) { s1 += __shfl_down(s1, o); s2 += __shfl_down(s2, o); }
    __shared__ float sr[8];
    if ((tid & 63) == 0) { sr[tid >> 6] = s1; sr[4 + (tid >> 6)] = s2; }
    __syncthreads();
    s1 = sr[0] + sr[1] + sr[2] + sr[3];
    s2 = sr[4] + sr[5] + sr[6] + sr[7];
    float mu = s1 * (1.f / 512.f);
    float var = s2 * (1.f / 512.f) - mu * mu;
    float inv = rsqrtf(var + 1e-6f);
    int e = tid * 2;
    float2 r;
    r.x = (ap[e] + 1.f) * ((vv.x - mu) * inv) + ap[512 + e];
    r.y = (ap[e + 1] + 1.f) * ((vv.y - mu) * inv) + ap[512 + e + 1];
    *(float2*)(out + (long)row * EDIM + e) = r;
}

// ---------------- residual: xout = xin + al*y/sqrt(1+al^2) ----------------
__global__ __launch_bounds__(256) void k_residual(const float* __restrict__ y, const float* __restrict__ ada,
                                                  const float* __restrict__ xin, float* __restrict__ xout, int lw) {
    int row = blockIdx.x; int b = row / NT;
    const float* al = ada + (long)(lw * 2 + b) * E3 + 1024;
    int e = threadIdx.x * 2;
    float a0 = al[e], a1 = al[e + 1];
    float2 yv = *(const float2*)(y + (long)row * EDIM + e);
    float2 xv = *(const float2*)(xin + (long)row * EDIM + e);
    float2 r;
    r.x = xv.x + a0 * rsqrtf(1.f + a0 * a0) * yv.x;
    r.y = xv.y + a1 * rsqrtf(1.f + a1 * a1) * yv.y;
    *(float2*)(xout + (long)row * EDIM + e) = r;
}

// ---------------- softmax over last dim (len 768), in place ----------------
__global__ __launch_bounds__(256) void k_softmax(float* __restrict__ logits) {
    float* p = logits + (long)blockIdx.x * NT;
    int tid = threadIdx.x;
    float v0 = p[tid], v1 = p[tid + 256], v2 = p[tid + 512];
    float mx = fmaxf(v0, fmaxf(v1, v2));
    for (int o = 32; o; o >>= 1) mx = fmaxf(mx, __shfl_down(mx, o));
    __shared__ float sr[8];
    if ((tid & 63) == 0) sr[tid >> 6] = mx;
    __syncthreads();
    mx = fmaxf(fmaxf(sr[0], sr[1]), fmaxf(sr[2], sr[3]));
    float e0 = __expf(v0 - mx), e1 = __expf(v1 - mx), e2 = __expf(v2 - mx);
    float s = e0 + e1 + e2;
    for (int o = 32; o; o >>= 1) s += __shfl_down(s, o);
    if ((tid & 63) == 0) sr[4 + (tid >> 6)] = s;
    __syncthreads();
    s = sr[4] + sr[5] + sr[6] + sr[7];
    float inv = 1.f / s;
    p[tid] = e0 * inv; p[tid + 256] = e1 * inv; p[tid + 512] = e2 * inv;
}

// ---------------- generic tiled GEMM ----------------
// C[M,N] = epi(A[M,K] @ B[K,N]).  BT: B stored [N][K] (compute A@B^T).
// EPI 0: +bias[n] (bias may be null); EPI 1: gelu(+bias[n]); EPI 2: *0.125 + biasmat[m*ldc+n]
// per-z offsets: ptr + (z>>3)*sB + (z&7)*sH
template<int EPI, bool BT>
__global__ __launch_bounds__(256) void k_gemm(const float* __restrict__ Abase, const float* __restrict__ Bbase,
        const float* __restrict__ biasbase, float* __restrict__ Cbase,
        int M, int N, int K, int lda, int ldb, int ldc,
        long aB, long aH, long bB, long bH, long cB, long cH, long biB, long biH) {
    int z = blockIdx.z; int zb = z >> 3, zh = z & 7;
    const float* A = Abase + zb * aB + zh * aH;
    const float* Bm = Bbase + zb * bB + zh * bH;
    const float* bias = biasbase ? (biasbase + zb * biB + zh * biH) : nullptr;
    float* C = Cbase + zb * cB + zh * cH;

    int m0 = blockIdx.y * 64, n0 = blockIdx.x * 64;
    __shared__ alignas(16) float As[16][64];
    __shared__ alignas(16) float Bs[16][64];
    int tid = threadIdx.x;
    int tx = tid & 15, ty = tid >> 4;
    int arow = tid >> 2, akc = (tid & 3) * 4;       // 64 rows x 16 k
    int brow = tid >> 4, bcol = (tid & 15) * 4;     // 16 k x 64 n
    float acc[4][4] = {};
    for (int k0 = 0; k0 < K; k0 += 16) {
        float4 av = *(const float4*)(A + (long)(m0 + arow) * lda + k0 + akc);
        As[akc + 0][arow] = av.x; As[akc + 1][arow] = av.y;
        As[akc + 2][arow] = av.z; As[akc + 3][arow] = av.w;
        if (!BT) {
            float4 bv = *(const float4*)(Bm + (long)(k0 + brow) * ldb + n0 + bcol);
            *(float4*)&Bs[brow][bcol] = bv;
        } else {
            float4 bv = *(const float4*)(Bm + (long)(n0 + arow) * ldb + k0 + akc);
            Bs[akc + 0][arow] = bv.x; Bs[akc + 1][arow] = bv.y;
            Bs[akc + 2][arow] = bv.z; Bs[akc + 3][arow] = bv.w;
        }
        __syncthreads();
        #pragma unroll
        for (int kk = 0; kk < 16; ++kk) {
            float4 a4 = *(const float4*)(&As[kk][ty * 4]);
            float4 b4 = *(const float4*)(&Bs[kk][tx * 4]);
            float a[4] = {a4.x, a4.y, a4.z, a4.w};
            float bb[4] = {b4.x, b4.y, b4.z, b4.w};
            #pragma unroll
            for (int i = 0; i < 4; ++i)
                #pragma unroll
                for (int j = 0; j < 4; ++j) acc[i][j] = fmaf(a[i], bb[j], acc[i][j]);
        }
        __syncthreads();
    }
    #pragma unroll
    for (int i = 0; i < 4; ++i) {
        int m = m0 + ty * 4 + i;
        float4 r;
        float* rp = &r.x;
        #pragma unroll
        for (int j = 0; j < 4; ++j) {
            float vv = acc[i][j];
            int n = n0 + tx * 4 + j;
            if (EPI == 0) { if (bias) vv += bias[n]; }
            else if (EPI == 1) {
                vv += bias[n];
                float u = vv;
                vv = 0.5f * u * (1.f + tanhf(0.7978845608028654f * (u + 0.044715f * u * u * u)));
            } else {
                vv = vv * 0.125f + bias[(long)m * ldc + n];
            }
            rp[j] = vv;
        }
        *(float4*)(C + (long)m * ldc + n0 + tx * 4) = r;
    }
}

extern "C" void kernel_launch(void* const* d_in, const int* in_sizes, int n_in,
                              void* d_out, int out_size, void* d_ws, size_t ws_size,
                              hipStream_t stream) {
    const float* x       = (const float*)d_in[0];
    const float* t       = (const float*)d_in[1];
    const float* vec_map = (const float*)d_in[2];
    const float* W_rb    = (const float*)d_in[3];
    const float* b_rb    = (const float*)d_in[4];
    const float* W_embed = (const float*)d_in[5];
    const float* b_embed = (const float*)d_in[6];
    const float* pos_emb = (const float*)d_in[7];
    const float* a1W1    = (const float*)d_in[8];
    const float* a1b1    = (const float*)d_in[9];
    const float* a1W2    = (const float*)d_in[10];
    const float* a1b2    = (const float*)d_in[11];
    const float* qkv_W   = (const float*)d_in[12];
    const float* qkv_b   = (const float*)d_in[13];
    const float* out_W   = (const float*)d_in[14];
    const float* out_b   = (const float*)d_in[15];
    const float* a2W1    = (const float*)d_in[16];
    const float* a2b1    = (const float*)d_in[17];
    const float* a2W2    = (const float*)d_in[18];
    const float* a2b2    = (const float*)d_in[19];
    const float* mlp_W1  = (const float*)d_in[20];
    const float* mlp_b1  = (const float*)d_in[21];
    const float* mlp_W2  = (const float*)d_in[22];
    const float* mlp_b2  = (const float*)d_in[23];

    float* ws = (float*)d_ws;
    float* v      = ws;                    // 4608
    float* biasT  = v + 4608;              // 9,437,184
    float* xc     = biasT + 9437184;       // 786,432
    float* ln     = xc + 786432;           // 786,432
    float* qkv    = ln + 786432;           // 2,359,296
    float* attnb  = qkv + 2359296;         // 786,432
    float* proj   = attnb + 786432;        // 786,432
    float* mlph   = proj + 786432;         // 3,145,728
    float* logits = mlph + 3145728;        // 9,437,184
    float* ada    = logits + 9437184;      // 24,576   -> total ~105 MB

    k_vnorm<<<6, 256, 0, stream>>>(vec_map, v);
    k_bias<<<TB * NT, 256, 0, stream>>>(v, W_rb, b_rb, biasT);
    k_embed<<<TB * NT, 256, 0, stream>>>(x, W_embed, b_embed, pos_emb, xc);
    k_adaln<<<16, 256, 0, stream>>>(t, a1W1, a1b1, a1W2, a1b2, a2W1, a2b1, a2W2, a2b2, ada);

    const long sQKVb = (long)NT * E3;      // qkv batch stride (b)
    const long sQKVh = 192;                // head stride within a qkv row
    const long sLb   = (long)NH * NT * NT; // logits b stride
    const long sLh   = (long)NT * NT;      // logits h stride

    for (int l = 0; l < 4; ++l) {
        int lw0 = l * 2, lw1 = l * 2 + 1;
        // --- attention half ---
        k_lnmod<<<TB * NT, 256, 0, stream>>>(xc, ada, ln, lw0);
        k_gemm<0, false><<<dim3(24, 24, 1), 256, 0, stream>>>(
            ln, qkv_W + (long)l * EDIM * E3, qkv_b + l * E3, qkv,
            TB * NT, E3, EDIM, EDIM, E3, E3, 0, 0, 0, 0, 0, 0, 0, 0);
        // QK^T * 1/8 + bias  (A=q, B=k stored [n][k] -> BT)
        k_gemm<2, true><<<dim3(12, 12, 16), 256, 0, stream>>>(
            qkv, qkv + 64, biasT, logits,
            NT, NT, HD, E3, E3, NT,
            sQKVb, sQKVh, sQKVb, sQKVh, sLb, sLh, sLb, sLh);
        k_softmax<<<TB * NH * NT, 256, 0, stream>>>(logits);
        // PV: A=probs, B=v rows [k][d]
        k_gemm<0, false><<<dim3(1, 12, 16), 256, 0, stream>>>(
            logits, qkv + 128, nullptr, attnb,
            NT, HD, NT, NT, E3, EDIM,
            sLb, sLh, sQKVb, sQKVh, (long)NT * EDIM, 64, 0, 0);
        k_gemm<0, false><<<dim3(8, 24, 1), 256, 0, stream>>>(
            attnb, out_W + (long)l * EDIM * EDIM, out_b + l * EDIM, proj,
            TB * NT, EDIM, EDIM, EDIM, EDIM, EDIM, 0, 0, 0, 0, 0, 0, 0, 0);
        k_residual<<<TB * NT, 256, 0, stream>>>(proj, ada, xc, xc, lw0);
        // --- mlp half ---
        k_lnmod<<<TB * NT, 256, 0, stream>>>(xc, ada, ln, lw1);
        k_gemm<1, false><<<dim3(32, 24, 1), 256, 0, stream>>>(
            ln, mlp_W1 + (long)l * EDIM * E4, mlp_b1 + l * E4, mlph,
            TB * NT, E4, EDIM, EDIM, E4, E4, 0, 0, 0, 0, 0, 0, 0, 0);
        k_gemm<0, false><<<dim3(8, 24, 1), 256, 0, stream>>>(
            mlph, mlp_W2 + (long)l * E4 * EDIM, mlp_b2 + l * EDIM, proj,
            TB * NT, EDIM, E4, E4, EDIM, EDIM, 0, 0, 0, 0, 0, 0, 0, 0);
        k_residual<<<TB * NT, 256, 0, stream>>>(proj, ada, xc,
            (l == 3) ? (float*)d_out : xc, lw1);
    }
}

// Round 2
// 734.418 us; speedup vs baseline: 2.1273x; 2.1273x over previous
//
#include <hip/hip_runtime.h>
#include <hip/hip_bf16.h>

// HEALPixTransformer: B=2, Nt=768, E=512, H=8, hd=64, T=256, F=64, L=4
// Round 2: bf16 MFMA GEMMs (16x16x32), global_load_lds staging, bf16 activations,
// fp32 residual stream. k_bias occupancy fix (unroll 4) + bf16 bias table.

#define NT 768
#define EDIM 512
#define E3 1536
#define E4 2048
#define NH 8
#define TB 2

typedef unsigned short ushort_t;
typedef __attribute__((ext_vector_type(8))) short bf16x8;
typedef __attribute__((ext_vector_type(4))) float f32x4;

__device__ inline float b2f(ushort_t u) {
    unsigned int i = ((unsigned int)u) << 16; float f;
    __builtin_memcpy(&f, &i, 4); return f;
}
__device__ inline ushort_t f2b(float f) {
    __hip_bfloat16 h = __float2bfloat16(f);
    ushort_t u; __builtin_memcpy(&u, &h, 2); return u;
}
__device__ inline float gelu_tanh(float u) {
    return 0.5f * u * (1.f + tanhf(0.7978845608028654f * (u + 0.044715f * u * u * u)));
}

// ---------------- vnorm ----------------
__global__ __launch_bounds__(256) void k_vnorm(const float* __restrict__ vm, float* __restrict__ v) {
    int idx = blockIdx.x * 256 + threadIdx.x;
    if (idx >= TB * NT) return;
    float s0 = 0.f, s1 = 0.f, s2 = 0.f;
    #pragma unroll
    for (int p = 0; p < 4; ++p) {
        s0 += vm[(idx * 4 + p) * 3 + 0];
        s1 += vm[(idx * 4 + p) * 3 + 1];
        s2 += vm[(idx * 4 + p) * 3 + 2];
    }
    float inv = 1.f / sqrtf(s0 * s0 + s1 * s1 + s2 * s2);
    v[idx * 3 + 0] = s0 * inv; v[idx * 3 + 1] = s1 * inv; v[idx * 3 + 2] = s2 * inv;
}

// ---------------- bias table (bf16 out): biasT[b][h][q][k] ----------------
__global__ __launch_bounds__(256) void k_bias(const float* __restrict__ v, const float* __restrict__ W_rb,
                                              const float* __restrict__ b_rb, ushort_t* __restrict__ biasT) {
    int bq = blockIdx.x; int b = bq / NT, q = bq % NT;
    __shared__ float sv[NT * 3];
    __shared__ float sw[64 * 8];
    __shared__ ushort_t sb[NT * 8];
    int tid = threadIdx.x;
    for (int i = tid; i < NT * 3; i += 256) sv[i] = v[b * NT * 3 + i];
    for (int i = tid; i < 512; i += 256) sw[i] = W_rb[i];
    __syncthreads();
    float vq0 = sv[q * 3], vq1 = sv[q * 3 + 1], vq2 = sv[q * 3 + 2];
    float br[8];
    #pragma unroll
    for (int h = 0; h < 8; ++h) br[h] = b_rb[h];
    for (int k = tid; k < NT; k += 256) {
        float d0 = vq0 - sv[k * 3], d1 = vq1 - sv[k * 3 + 1], d2 = vq2 - sv[k * 3 + 2];
        float dot = 1.f - 0.5f * (d0 * d0 + d1 * d1 + d2 * d2);
        dot = fminf(1.f, fmaxf(-1.f, dot));
        float base = acosf(dot) * 200.f * (10.f / 31.f);
        float acc[8];
        #pragma unroll
        for (int h = 0; h < 8; ++h) acc[h] = br[h];
        #pragma unroll 4
        for (int f = 0; f < 32; ++f) {
            float sn, cs;
            __sincosf(base * (float)f, &sn, &cs);
            #pragma unroll
            for (int h = 0; h < 8; ++h) acc[h] += sn * sw[f * 8 + h] + cs * sw[(f + 32) * 8 + h];
        }
        #pragma unroll
        for (int h = 0; h < 8; ++h) sb[k * 8 + h] = f2b(acc[h]);
    }
    __syncthreads();
    long basep = (long)(b * 8) * NT * NT + (long)q * NT;
    for (int h = 0; h < 8; ++h)
        for (int k = tid; k < NT; k += 256)
            biasT[basep + (long)h * NT * NT + k] = sb[k * 8 + h];
}

// ---------------- embed (fp32 out) ----------------
__global__ __launch_bounds__(256) void k_embed(const float* __restrict__ x, const float* __restrict__ W,
                                               const float* __restrict__ be, const float* __restrict__ pe,
                                               float* __restrict__ xc) {
    int row = blockIdx.x; int nt = row % NT;
    __shared__ float sx[16];
    int tid = threadIdx.x;
    if (tid < 16) sx[tid] = x[row * 16 + tid];
    __syncthreads();
    for (int e = tid; e < EDIM; e += 256) {
        float a = be[e] + pe[nt * EDIM + e];
        #pragma unroll
        for (int j = 0; j < 16; ++j) a += sx[j] * W[j * EDIM + e];
        xc[(long)row * EDIM + e] = a;
    }
}

// ---------------- adaLN precompute: ada[(l*2+w)*2+b][1536], grid (16, 6) ----------------
__global__ __launch_bounds__(256) void k_adaln(const float* __restrict__ t,
    const float* __restrict__ a1W1, const float* __restrict__ a1b1, const float* __restrict__ a1W2, const float* __restrict__ a1b2,
    const float* __restrict__ a2W1, const float* __restrict__ a2b1, const float* __restrict__ a2W2, const float* __restrict__ a2b2,
    float* __restrict__ ada) {
    int blk = blockIdx.x; int b = blk & 1, lw = blk >> 1; int which = lw & 1, l = lw >> 1;
    const float* W1 = (which ? a2W1 : a1W1) + (long)l * 256 * 256;
    const float* b1 = (which ? a2b1 : a1b1) + l * 256;
    const float* W2 = (which ? a2W2 : a1W2) + (long)l * 256 * E3;
    const float* b2 = (which ? a2b2 : a1b2) + l * E3;
    __shared__ float st[256], sh[256];
    int tid = threadIdx.x;
    st[tid] = t[b * 256 + tid];
    __syncthreads();
    float a = b1[tid];
    for (int i = 0; i < 256; ++i) a += st[i] * W1[i * 256 + tid];
    sh[tid] = a / (1.f + __expf(-a));
    __syncthreads();
    int c = blockIdx.y * 256 + tid;
    float m = b2[c];
    for (int i = 0; i < 256; ++i) m += sh[i] * W2[i * E3 + c];
    ada[(long)(lw * 2 + b) * E3 + c] = m;
}

// ---------------- LN + modulate (bf16 out) ----------------
__global__ __launch_bounds__(256) void k_lnmod(const float* __restrict__ xc, const float* __restrict__ ada,
                                               ushort_t* __restrict__ out, int lw) {
    int row = blockIdx.x; int b = row / NT;
    const float* ap = ada + (long)(lw * 2 + b) * E3;
    int tid = threadIdx.x;
    float2 vv = *(const float2*)(xc + (long)row * EDIM + tid * 2);
    float s1 = vv.x + vv.y, s2 = vv.x * vv.x + vv.y * vv.y;
    for (int o = 32; o; o >>= 1) { s1 += __shfl_down(s1, o); s2 += __shfl_down(s2, o); }
    __shared__ float sr[8];
    if ((tid & 63) == 0) { sr[tid >> 6] = s1; sr[4 + (tid >> 6)] = s2; }
    __syncthreads();
    s1 = sr[0] + sr[1] + sr[2] + sr[3];
    s2 = sr[4] + sr[5] + sr[6] + sr[7];
    float mu = s1 * (1.f / 512.f);
    float var = s2 * (1.f / 512.f) - mu * mu;
    float inv = rsqrtf(var + 1e-6f);
    int e = tid * 2;
    float r0 = (ap[e] + 1.f) * ((vv.x - mu) * inv) + ap[512 + e];
    float r1 = (ap[e + 1] + 1.f) * ((vv.y - mu) * inv) + ap[512 + e + 1];
    unsigned int pk = (unsigned int)f2b(r0) | ((unsigned int)f2b(r1) << 16);
    ((unsigned int*)out)[(long)row * 256 + tid] = pk;
}

// ---------------- residual (fp32) ----------------
__global__ __launch_bounds__(256) void k_residual(const float* __restrict__ y, const float* __restrict__ ada,
                                                  const float* __restrict__ xin, float* __restrict__ xout, int lw) {
    int row = blockIdx.x; int b = row / NT;
    const float* al = ada + (long)(lw * 2 + b) * E3 + 1024;
    int e = threadIdx.x * 2;
    float a0 = al[e], a1 = al[e + 1];
    float2 yv = *(const float2*)(y + (long)row * EDIM + e);
    float2 xv = *(const float2*)(xin + (long)row * EDIM + e);
    float2 r;
    r.x = xv.x + a0 * rsqrtf(1.f + a0 * a0) * yv.x;
    r.y = xv.y + a1 * rsqrtf(1.f + a1 * a1) * yv.y;
    *(float2*)(xout + (long)row * EDIM + e) = r;
}

// ---------------- softmax: fp32 row -> bf16 row in place ----------------
__global__ __launch_bounds__(256) void k_softmax(float* __restrict__ logits) {
    float* p = logits + (long)blockIdx.x * NT;
    ushort_t* pb = (ushort_t*)p;
    int tid = threadIdx.x;
    float v0 = p[tid], v1 = p[tid + 256], v2 = p[tid + 512];
    float mx = fmaxf(v0, fmaxf(v1, v2));
    for (int o = 32; o; o >>= 1) mx = fmaxf(mx, __shfl_down(mx, o));
    __shared__ float sr[8];
    if ((tid & 63) == 0) sr[tid >> 6] = mx;
    __syncthreads();
    mx = fmaxf(fmaxf(sr[0], sr[1]), fmaxf(sr[2], sr[3]));
    float e0 = __expf(v0 - mx), e1 = __expf(v1 - mx), e2 = __expf(v2 - mx);
    float s = e0 + e1 + e2;
    for (int o = 32; o; o >>= 1) s += __shfl_down(s, o);
    if ((tid & 63) == 0) sr[4 + (tid >> 6)] = s;
    __syncthreads();
    s = sr[4] + sr[5] + sr[6] + sr[7];
    float inv = 1.f / s;
    pb[tid] = f2b(e0 * inv); pb[tid + 256] = f2b(e1 * inv); pb[tid + 512] = f2b(e2 * inv);
}

// ---------------- weight convert+transpose: W[K][N] fp32 -> Wt[N][K] bf16 ----------------
__global__ __launch_bounds__(256) void k_wT(const float* __restrict__ W, ushort_t* __restrict__ Wt,
                                            int Kd, int Nd) {
    const float* Wp = W + (long)blockIdx.z * Kd * Nd;
    ushort_t* Wtp = Wt + (long)blockIdx.z * Kd * Nd;
    int n0 = blockIdx.x * 64, k0 = blockIdx.y * 64;
    __shared__ float s[64][65];
    int tid = threadIdx.x;
    #pragma unroll
    for (int it = 0; it < 4; ++it) {
        int idx = tid + it * 256;
        int r = idx >> 4, c4 = (idx & 15) * 4;
        float4 vv = *(const float4*)(Wp + (long)(k0 + r) * Nd + n0 + c4);
        s[r][c4] = vv.x; s[r][c4 + 1] = vv.y; s[r][c4 + 2] = vv.z; s[r][c4 + 3] = vv.w;
    }
    __syncthreads();
    #pragma unroll
    for (int it = 0; it < 4; ++it) {
        int idx = tid + it * 256;
        int rn = idx >> 4, ck = (idx & 15) * 4;
        long base = (long)(n0 + rn) * Kd + k0 + ck;
        #pragma unroll
        for (int j = 0; j < 4; ++j) Wtp[base + j] = f2b(s[ck + j][rn]);
    }
}

// ---------------- v transpose: qkv[b][nt][h*192+128+d] -> vT[bh][d][nt] ----------------
__global__ __launch_bounds__(256) void k_vT(const ushort_t* __restrict__ qkv16, ushort_t* __restrict__ vT) {
    int bh = blockIdx.y; int b = bh >> 3, h = bh & 7;
    int nt0 = blockIdx.x * 64;
    __shared__ ushort_t s[64][80];
    int tid = threadIdx.x;
    #pragma unroll
    for (int it = 0; it < 2; ++it) {
        int idx = tid + it * 256;
        int rnt = idx >> 3, c8 = (idx & 7) * 8;
        bf16x8 vv = *(const bf16x8*)(qkv16 + ((long)(b * NT + nt0 + rnt) * E3 + h * 192 + 128 + c8));
        *(bf16x8*)&s[rnt][c8] = vv;
    }
    __syncthreads();
    #pragma unroll
    for (int it = 0; it < 2; ++it) {
        int idx = tid + it * 256;
        int d = idx >> 3, n8 = (idx & 7) * 8;
        ushort_t tmp[8];
        #pragma unroll
        for (int j = 0; j < 8; ++j) tmp[j] = s[n8 + j][d];
        bf16x8 ov; __builtin_memcpy(&ov, tmp, 16);
        *(bf16x8*)(vT + ((long)bh * 64 + d) * NT + nt0 + n8) = ov;
    }
}

// ---------------- MFMA GEMM ----------------
// C[M,N] = epi(A[M,K] @ Bt[N,K]^T).  A, Bt bf16 with K contiguous.
// EPI 0: bf16 out, +bias[n] (float, may be null)     EPI 1: bf16 out, gelu(+bias[n])
// EPI 2: fp32 out, *0.125 + bf16 biasmat[m*ldbias+n] EPI 3: fp32 out, +bias[n]
__device__ inline void stC(float* C, long i, float v) { C[i] = v; }
__device__ inline void stC(ushort_t* C, long i, float v) { C[i] = f2b(v); }

template<int FM, int FN, int EPI, typename CT>
__global__ __launch_bounds__(256) void k_mm(
        const ushort_t* __restrict__ Abase, const ushort_t* __restrict__ Bbase,
        const void* __restrict__ biasbase, CT* __restrict__ Cbase,
        int K, int lda, int ldb, int ldc, int ldbias,
        long aB, long aH, long bB, long bH, long cB, long cH, long biB, long biH) {
    constexpr int BM = FM * 32, BN = FN * 32;
    constexpr int NCHA = BM / 16, NCH = (BM + BN) / 16, NPW = NCH / 4;
    int z = blockIdx.z, zb = z >> 3, zh = z & 7;
    const ushort_t* A = Abase + zb * aB + zh * aH;
    const ushort_t* B = Bbase + zb * bB + zh * bH;
    CT* C = Cbase + zb * cB + zh * cH;

    __shared__ __align__(16) ushort_t As[BM][32];
    __shared__ __align__(16) ushort_t Bs[BN][32];

    int tid = threadIdx.x, lane = tid & 63, wave = tid >> 6;
    int wm = wave >> 1, wn = wave & 1;
    int m0 = blockIdx.y * BM, n0 = blockIdx.x * BN;
    int srow = lane >> 2, scol = (lane & 3) * 8;

    f32x4 acc[FM][FN];
    #pragma unroll
    for (int i = 0; i < FM; ++i)
        #pragma unroll
        for (int j = 0; j < FN; ++j) acc[i][j] = f32x4{0.f, 0.f, 0.f, 0.f};

    for (int k0 = 0; k0 < K; k0 += 32) {
        #pragma unroll
        for (int c0 = 0; c0 < NPW; ++c0) {
            int c = wave * NPW + c0;
            const ushort_t* src;
            ushort_t* dst;
            if (c < NCHA) {
                src = A + (long)(m0 + c * 16 + srow) * lda + k0 + scol;
                dst = &As[c * 16][0];
            } else {
                int cc = c - NCHA;
                src = B + (long)(n0 + cc * 16 + srow) * ldb + k0 + scol;
                dst = &Bs[cc * 16][0];
            }
            __builtin_amdgcn_global_load_lds(
                (const __attribute__((address_space(1))) unsigned int*)src,
                (__attribute__((address_space(3))) unsigned int*)dst, 16, 0, 0);
        }
        __syncthreads();
        int r = lane & 15, g = lane >> 4;
        bf16x8 af[FM], bfr[FN];
        #pragma unroll
        for (int i = 0; i < FM; ++i) af[i] = *(const bf16x8*)&As[wm * FM * 16 + i * 16 + r][g * 8];
        #pragma unroll
        for (int j = 0; j < FN; ++j) bfr[j] = *(const bf16x8*)&Bs[wn * FN * 16 + j * 16 + r][g * 8];
        #pragma unroll
        for (int i = 0; i < FM; ++i)
            #pragma unroll
            for (int j = 0; j < FN; ++j)
                acc[i][j] = __builtin_amdgcn_mfma_f32_16x16x32_bf16(af[i], bfr[j], acc[i][j], 0, 0, 0);
        __syncthreads();
    }

    int gr = (lane >> 4) * 4, cL = lane & 15;
    #pragma unroll
    for (int i = 0; i < FM; ++i) {
        int mB = m0 + wm * FM * 16 + i * 16 + gr;
        #pragma unroll
        for (int j = 0; j < FN; ++j) {
            int n = n0 + wn * FN * 16 + j * 16 + cL;
            float bn = 0.f;
            if constexpr (EPI == 0 || EPI == 1 || EPI == 3) {
                if (biasbase) bn = ((const float*)biasbase)[n];
            }
            #pragma unroll
            for (int rr = 0; rr < 4; ++rr) {
                float vv = acc[i][j][rr];
                long cidx = (long)(mB + rr) * ldc + n;
                if constexpr (EPI == 0) {
                    stC(C, cidx, vv + bn);
                } else if constexpr (EPI == 1) {
                    stC(C, cidx, gelu_tanh(vv + bn));
                } else if constexpr (EPI == 2) {
                    const ushort_t* bp = (const ushort_t*)biasbase + zb * biB + zh * biH;
                    stC(C, cidx, vv * 0.125f + b2f(bp[(long)(mB + rr) * ldbias + n]));
                } else {
                    stC(C, cidx, vv + bn);
                }
            }
        }
    }
}

extern "C" void kernel_launch(void* const* d_in, const int* in_sizes, int n_in,
                              void* d_out, int out_size, void* d_ws, size_t ws_size,
                              hipStream_t stream) {
    const float* x       = (const float*)d_in[0];
    const float* t       = (const float*)d_in[1];
    const float* vec_map = (const float*)d_in[2];
    const float* W_rb    = (const float*)d_in[3];
    const float* b_rb    = (const float*)d_in[4];
    const float* W_embed = (const float*)d_in[5];
    const float* b_embed = (const float*)d_in[6];
    const float* pos_emb = (const float*)d_in[7];
    const float* a1W1    = (const float*)d_in[8];
    const float* a1b1    = (const float*)d_in[9];
    const float* a1W2    = (const float*)d_in[10];
    const float* a1b2    = (const float*)d_in[11];
    const float* qkv_W   = (const float*)d_in[12];
    const float* qkv_b   = (const float*)d_in[13];
    const float* out_W   = (const float*)d_in[14];
    const float* out_b   = (const float*)d_in[15];
    const float* a2W1    = (const float*)d_in[16];
    const float* a2b1    = (const float*)d_in[17];
    const float* a2W2    = (const float*)d_in[18];
    const float* a2b2    = (const float*)d_in[19];
    const float* mlp_W1  = (const float*)d_in[20];
    const float* mlp_b1  = (const float*)d_in[21];
    const float* mlp_W2  = (const float*)d_in[22];
    const float* mlp_b2  = (const float*)d_in[23];

    float* ws = (float*)d_ws;
    size_t o = 0;
    float* v       = ws + o; o += 8192;
    ushort_t* biasT = (ushort_t*)(ws + o); o += 4718592;   // 16*768*768 bf16
    float* logits  = ws + o; o += 9437184;                 // 16*768*768 f32 (reused as bf16 probs)
    float* ada     = ws + o; o += 24576;
    float* xc      = ws + o; o += 786432;
    float* proj    = ws + o; o += 786432;
    ushort_t* ln16  = (ushort_t*)(ws + o); o += 393216;    // 1536x512
    ushort_t* qkv16 = (ushort_t*)(ws + o); o += 1179648;   // 1536x1536
    ushort_t* vT    = (ushort_t*)(ws + o); o += 393216;    // 16x64x768
    ushort_t* attnb = (ushort_t*)(ws + o); o += 393216;    // 1536x512
    ushort_t* mlph  = (ushort_t*)(ws + o); o += 1572864;   // 1536x2048
    ushort_t* qkvWt = (ushort_t*)(ws + o); o += 1572864;   // 4x1536x512
    ushort_t* outWt = (ushort_t*)(ws + o); o += 524288;    // 4x512x512
    ushort_t* mlp1Wt = (ushort_t*)(ws + o); o += 2097152;  // 4x2048x512
    ushort_t* mlp2Wt = (ushort_t*)(ws + o); o += 2097152;  // 4x512x2048

    k_vnorm<<<6, 256, 0, stream>>>(vec_map, v);
    k_bias<<<TB * NT, 256, 0, stream>>>(v, W_rb, b_rb, biasT);
    k_embed<<<TB * NT, 256, 0, stream>>>(x, W_embed, b_embed, pos_emb, xc);
    k_adaln<<<dim3(16, 6), 256, 0, stream>>>(t, a1W1, a1b1, a1W2, a1b2, a2W1, a2b1, a2W2, a2b2, ada);
    k_wT<<<dim3(24, 8, 4), 256, 0, stream>>>(qkv_W,  qkvWt,  512, 1536);
    k_wT<<<dim3(8,  8, 4), 256, 0, stream>>>(out_W,  outWt,  512, 512);
    k_wT<<<dim3(32, 8, 4), 256, 0, stream>>>(mlp_W1, mlp1Wt, 512, 2048);
    k_wT<<<dim3(8, 32, 4), 256, 0, stream>>>(mlp_W2, mlp2Wt, 2048, 512);

    const long qB = (long)NT * E3, qH = 192;               // qkv16 strides (elems)
    const long lB = (long)NH * NT * NT, lH = (long)NT * NT; // logits f32 / biasT strides
    const long pB = 2 * lB, pH = 2 * lH;                   // probs-as-bf16 strides in logits buffer

    for (int l = 0; l < 4; ++l) {
        int lw0 = l * 2, lw1 = l * 2 + 1;
        // attention half
        k_lnmod<<<TB * NT, 256, 0, stream>>>(xc, ada, ln16, lw0);
        k_mm<4, 4, 0, ushort_t><<<dim3(12, 12, 1), 256, 0, stream>>>(
            ln16, qkvWt + (long)l * 786432, qkv_b + l * E3, qkv16,
            512, 512, 512, E3, 0, 0, 0, 0, 0, 0, 0, 0, 0);
        k_vT<<<dim3(12, 16), 256, 0, stream>>>(qkv16, vT);
        k_mm<4, 4, 2, float><<<dim3(6, 6, 16), 256, 0, stream>>>(
            qkv16, qkv16 + 64, biasT, logits,
            64, E3, E3, NT, NT, qB, qH, qB, qH, lB, lH, lB, lH);
        k_softmax<<<TB * NH * NT, 256, 0, stream>>>(logits);
        k_mm<4, 2, 0, ushort_t><<<dim3(1, 6, 16), 256, 0, stream>>>(
            (const ushort_t*)logits, vT, nullptr, attnb,
            768, E3, NT, EDIM, 0, pB, pH, (long)NH * 64 * NT, (long)64 * NT, (long)NT * EDIM, 64, 0, 0);
        k_mm<4, 4, 3, float><<<dim3(4, 12, 1), 256, 0, stream>>>(
            attnb, outWt + (long)l * 262144, out_b + l * EDIM, proj,
            512, 512, 512, EDIM, 0, 0, 0, 0, 0, 0, 0, 0, 0);
        k_residual<<<TB * NT, 256, 0, stream>>>(proj, ada, xc, xc, lw0);
        // mlp half
        k_lnmod<<<TB * NT, 256, 0, stream>>>(xc, ada, ln16, lw1);
        k_mm<4, 4, 1, ushort_t><<<dim3(16, 12, 1), 256, 0, stream>>>(
            ln16, mlp1Wt + (long)l * 1048576, mlp_b1 + l * E4, mlph,
            512, 512, 512, E4, 0, 0, 0, 0, 0, 0, 0, 0, 0);
        k_mm<4, 4, 3, float><<<dim3(4, 12, 1), 256, 0, stream>>>(
            mlph, mlp2Wt + (long)l * 1048576, mlp_b2 + l * EDIM, proj,
            2048, 2048, 2048, EDIM, 0, 0, 0, 0, 0, 0, 0, 0, 0);
        k_residual<<<TB * NT, 256, 0, stream>>>(proj, ada, xc,
            (l == 3) ? (float*)d_out : xc, lw1);
    }
}

// Round 3
// 546.696 us; speedup vs baseline: 2.8578x; 1.3434x over previous
//
#include <hip/hip_runtime.h>
#include <hip/hip_bf16.h>

// HEALPixTransformer: B=2, Nt=768, E=512, H=8, hd=64, T=256, F=64, L=4
// Round 3: 64x64-tile MFMA GEMM (K-step 64, XOR bank swizzle, global_load_lds),
// split-K for thin GEMMs (out/mlp2/PV) with fused reduce+residual epilogue,
// sincos recurrence in k_bias.

#define NT 768
#define EDIM 512
#define E3 1536
#define E4 2048
#define NH 8
#define TB 2

typedef unsigned short ushort_t;
typedef __attribute__((ext_vector_type(8))) short bf16x8;
typedef __attribute__((ext_vector_type(4))) float f32x4;

__device__ inline float b2f(ushort_t u) {
    unsigned int i = ((unsigned int)u) << 16; float f;
    __builtin_memcpy(&f, &i, 4); return f;
}
__device__ inline ushort_t f2b(float f) {
    __hip_bfloat16 h = __float2bfloat16(f);
    ushort_t u; __builtin_memcpy(&u, &h, 2); return u;
}
__device__ inline float gelu_tanh(float u) {
    float z = 1.5957691216057308f * (u + 0.044715f * u * u * u); // 2*0.79788456...
    z = fminf(z, 40.f);
    float t = __expf(z);
    float th = (t - 1.f) / (t + 1.f);
    return 0.5f * u * (1.f + th);
}

// ---------------- vnorm ----------------
__global__ __launch_bounds__(256) void k_vnorm(const float* __restrict__ vm, float* __restrict__ v) {
    int idx = blockIdx.x * 256 + threadIdx.x;
    if (idx >= TB * NT) return;
    float s0 = 0.f, s1 = 0.f, s2 = 0.f;
    #pragma unroll
    for (int p = 0; p < 4; ++p) {
        s0 += vm[(idx * 4 + p) * 3 + 0];
        s1 += vm[(idx * 4 + p) * 3 + 1];
        s2 += vm[(idx * 4 + p) * 3 + 2];
    }
    float inv = 1.f / sqrtf(s0 * s0 + s1 * s1 + s2 * s2);
    v[idx * 3 + 0] = s0 * inv; v[idx * 3 + 1] = s1 * inv; v[idx * 3 + 2] = s2 * inv;
}

// ---------------- bias table (bf16): biasT[b][h][q][k] ----------------
__global__ __launch_bounds__(256) void k_bias(const float* __restrict__ v, const float* __restrict__ W_rb,
                                              const float* __restrict__ b_rb, ushort_t* __restrict__ biasT) {
    int bq = blockIdx.x; int b = bq / NT, q = bq % NT;
    __shared__ float sv[NT * 3];
    __shared__ float sw[64 * 8];
    __shared__ ushort_t sb[NT * 8];
    int tid = threadIdx.x;
    for (int i = tid; i < NT * 3; i += 256) sv[i] = v[b * NT * 3 + i];
    for (int i = tid; i < 512; i += 256) sw[i] = W_rb[i];
    __syncthreads();
    float vq0 = sv[q * 3], vq1 = sv[q * 3 + 1], vq2 = sv[q * 3 + 2];
    float br[8];
    #pragma unroll
    for (int h = 0; h < 8; ++h) br[h] = b_rb[h];
    for (int k = tid; k < NT; k += 256) {
        float d0 = vq0 - sv[k * 3], d1 = vq1 - sv[k * 3 + 1], d2 = vq2 - sv[k * 3 + 2];
        float dot = 1.f - 0.5f * (d0 * d0 + d1 * d1 + d2 * d2);
        dot = fminf(1.f, fmaxf(-1.f, dot));
        float theta = acosf(dot) * (2000.f / 31.f);   // *200 * 10/31
        float s1, c1; __sincosf(theta, &s1, &c1);
        float sn = 0.f, cs = 1.f;                     // sin/cos of f*theta, f=0
        float acc[8];
        #pragma unroll
        for (int h = 0; h < 8; ++h) acc[h] = br[h];
        for (int f = 0; f < 32; ++f) {
            #pragma unroll
            for (int h = 0; h < 8; ++h) acc[h] += sn * sw[f * 8 + h] + cs * sw[(f + 32) * 8 + h];
            float ns = sn * c1 + cs * s1;
            cs = cs * c1 - sn * s1;
            sn = ns;
        }
        #pragma unroll
        for (int h = 0; h < 8; ++h) sb[k * 8 + h] = f2b(acc[h]);
    }
    __syncthreads();
    long basep = (long)(b * 8) * NT * NT + (long)q * NT;
    for (int h = 0; h < 8; ++h)
        for (int k = tid; k < NT; k += 256)
            biasT[basep + (long)h * NT * NT + k] = sb[k * 8 + h];
}

// ---------------- embed ----------------
__global__ __launch_bounds__(256) void k_embed(const float* __restrict__ x, const float* __restrict__ W,
                                               const float* __restrict__ be, const float* __restrict__ pe,
                                               float* __restrict__ xc) {
    int row = blockIdx.x; int nt = row % NT;
    __shared__ float sx[16];
    int tid = threadIdx.x;
    if (tid < 16) sx[tid] = x[row * 16 + tid];
    __syncthreads();
    for (int e = tid; e < EDIM; e += 256) {
        float a = be[e] + pe[nt * EDIM + e];
        #pragma unroll
        for (int j = 0; j < 16; ++j) a += sx[j] * W[j * EDIM + e];
        xc[(long)row * EDIM + e] = a;
    }
}

// ---------------- adaLN precompute ----------------
__global__ __launch_bounds__(256) void k_adaln(const float* __restrict__ t,
    const float* __restrict__ a1W1, const float* __restrict__ a1b1, const float* __restrict__ a1W2, const float* __restrict__ a1b2,
    const float* __restrict__ a2W1, const float* __restrict__ a2b1, const float* __restrict__ a2W2, const float* __restrict__ a2b2,
    float* __restrict__ ada) {
    int blk = blockIdx.x; int b = blk & 1, lw = blk >> 1; int which = lw & 1, l = lw >> 1;
    const float* W1 = (which ? a2W1 : a1W1) + (long)l * 256 * 256;
    const float* b1 = (which ? a2b1 : a1b1) + l * 256;
    const float* W2 = (which ? a2W2 : a1W2) + (long)l * 256 * E3;
    const float* b2 = (which ? a2b2 : a1b2) + l * E3;
    __shared__ float st[256], sh[256];
    int tid = threadIdx.x;
    st[tid] = t[b * 256 + tid];
    __syncthreads();
    float a = b1[tid];
    for (int i = 0; i < 256; ++i) a += st[i] * W1[i * 256 + tid];
    sh[tid] = a / (1.f + __expf(-a));
    __syncthreads();
    int c = blockIdx.y * 256 + tid;
    float m = b2[c];
    for (int i = 0; i < 256; ++i) m += sh[i] * W2[i * E3 + c];
    ada[(long)(lw * 2 + b) * E3 + c] = m;
}

// ---------------- LN + modulate (bf16 out) ----------------
__global__ __launch_bounds__(256) void k_lnmod(const float* __restrict__ xc, const float* __restrict__ ada,
                                               ushort_t* __restrict__ out, int lw) {
    int row = blockIdx.x; int b = row / NT;
    const float* ap = ada + (long)(lw * 2 + b) * E3;
    int tid = threadIdx.x;
    float2 vv = *(const float2*)(xc + (long)row * EDIM + tid * 2);
    float s1 = vv.x + vv.y, s2 = vv.x * vv.x + vv.y * vv.y;
    for (int o = 32; o; o >>= 1) { s1 += __shfl_down(s1, o); s2 += __shfl_down(s2, o); }
    __shared__ float sr[8];
    if ((tid & 63) == 0) { sr[tid >> 6] = s1; sr[4 + (tid >> 6)] = s2; }
    __syncthreads();
    s1 = sr[0] + sr[1] + sr[2] + sr[3];
    s2 = sr[4] + sr[5] + sr[6] + sr[7];
    float mu = s1 * (1.f / 512.f);
    float var = s2 * (1.f / 512.f) - mu * mu;
    float inv = rsqrtf(var + 1e-6f);
    int e = tid * 2;
    float r0 = (ap[e] + 1.f) * ((vv.x - mu) * inv) + ap[512 + e];
    float r1 = (ap[e + 1] + 1.f) * ((vv.y - mu) * inv) + ap[512 + e + 1];
    unsigned int pk = (unsigned int)f2b(r0) | ((unsigned int)f2b(r1) << 16);
    ((unsigned int*)out)[(long)row * 256 + tid] = pk;
}

// ---------------- softmax: fp32 row -> bf16 row in place ----------------
__global__ __launch_bounds__(256) void k_softmax(float* __restrict__ logits) {
    float* p = logits + (long)blockIdx.x * NT;
    ushort_t* pb = (ushort_t*)p;
    int tid = threadIdx.x;
    float v0 = p[tid], v1 = p[tid + 256], v2 = p[tid + 512];
    float mx = fmaxf(v0, fmaxf(v1, v2));
    for (int o = 32; o; o >>= 1) mx = fmaxf(mx, __shfl_down(mx, o));
    __shared__ float sr[8];
    if ((tid & 63) == 0) sr[tid >> 6] = mx;
    __syncthreads();
    mx = fmaxf(fmaxf(sr[0], sr[1]), fmaxf(sr[2], sr[3]));
    float e0 = __expf(v0 - mx), e1 = __expf(v1 - mx), e2 = __expf(v2 - mx);
    float s = e0 + e1 + e2;
    for (int o = 32; o; o >>= 1) s += __shfl_down(s, o);
    if ((tid & 63) == 0) sr[4 + (tid >> 6)] = s;
    __syncthreads();
    s = sr[4] + sr[5] + sr[6] + sr[7];
    float inv = 1.f / s;
    pb[tid] = f2b(e0 * inv); pb[tid + 256] = f2b(e1 * inv); pb[tid + 512] = f2b(e2 * inv);
}

// ---------------- weight convert+transpose: W[K][N] fp32 -> Wt[N][K] bf16 ----------------
__global__ __launch_bounds__(256) void k_wT(const float* __restrict__ W, ushort_t* __restrict__ Wt,
                                            int Kd, int Nd) {
    const float* Wp = W + (long)blockIdx.z * Kd * Nd;
    ushort_t* Wtp = Wt + (long)blockIdx.z * Kd * Nd;
    int n0 = blockIdx.x * 64, k0 = blockIdx.y * 64;
    __shared__ float s[64][65];
    int tid = threadIdx.x;
    #pragma unroll
    for (int it = 0; it < 4; ++it) {
        int idx = tid + it * 256;
        int r = idx >> 4, c4 = (idx & 15) * 4;
        float4 vv = *(const float4*)(Wp + (long)(k0 + r) * Nd + n0 + c4);
        s[r][c4] = vv.x; s[r][c4 + 1] = vv.y; s[r][c4 + 2] = vv.z; s[r][c4 + 3] = vv.w;
    }
    __syncthreads();
    #pragma unroll
    for (int it = 0; it < 4; ++it) {
        int idx = tid + it * 256;
        int rn = idx >> 4, ck = (idx & 15) * 4;
        long base = (long)(n0 + rn) * Kd + k0 + ck;
        #pragma unroll
        for (int j = 0; j < 4; ++j) Wtp[base + j] = f2b(s[ck + j][rn]);
    }
}

// ---------------- v transpose: qkv[b][nt][h*192+128+d] -> vT[bh][d][nt] ----------------
__global__ __launch_bounds__(256) void k_vT(const ushort_t* __restrict__ qkv16, ushort_t* __restrict__ vT) {
    int bh = blockIdx.y; int b = bh >> 3, h = bh & 7;
    int nt0 = blockIdx.x * 64;
    __shared__ ushort_t s[64][80];
    int tid = threadIdx.x;
    #pragma unroll
    for (int it = 0; it < 2; ++it) {
        int idx = tid + it * 256;
        int rnt = idx >> 3, c8 = (idx & 7) * 8;
        bf16x8 vv = *(const bf16x8*)(qkv16 + ((long)(b * NT + nt0 + rnt) * E3 + h * 192 + 128 + c8));
        *(bf16x8*)&s[rnt][c8] = vv;
    }
    __syncthreads();
    #pragma unroll
    for (int it = 0; it < 2; ++it) {
        int idx = tid + it * 256;
        int d = idx >> 3, n8 = (idx & 7) * 8;
        ushort_t tmp[8];
        #pragma unroll
        for (int j = 0; j < 8; ++j) tmp[j] = s[n8 + j][d];
        bf16x8 ov; __builtin_memcpy(&ov, tmp, 16);
        *(bf16x8*)(vT + ((long)bh * 64 + d) * NT + nt0 + n8) = ov;
    }
}

// ---------------- MFMA GEMM, 64x64 tile, K-step 64, XOR swizzle, split-K ----------------
// C[M,N] = epi(A[M,K] @ Bt[N,K]^T).  blockIdx.z = batch*kSplit + kc.
// EPI 0: bf16 out, +bias[n]   EPI 1: bf16 out, gelu(+bias[n])
// EPI 2: fp32 out, *0.125 + bf16 biasmat   EPI 4: fp32 raw partial at +kc*kcStride
__device__ inline void stC(float* C, long i, float v) { C[i] = v; }
__device__ inline void stC(ushort_t* C, long i, float v) { C[i] = f2b(v); }

template<int EPI, typename CT>
__global__ __launch_bounds__(256) void k_mm64(
        const ushort_t* __restrict__ A0, const ushort_t* __restrict__ B0,
        const void* __restrict__ biasbase, CT* __restrict__ C0,
        int Kchunk, int kSplit, int lda, int ldb, int ldc, int ldbias,
        long aB, long aH, long bB, long bH, long cB, long cH, long biB, long biH, long kcStride) {
    int z = blockIdx.z;
    int batch = z / kSplit, kc = z - batch * kSplit;
    int zb = batch >> 3, zh = batch & 7;
    const ushort_t* A = A0 + zb * aB + zh * aH + (long)kc * Kchunk;
    const ushort_t* B = B0 + zb * bB + zh * bH + (long)kc * Kchunk;
    CT* C = C0 + zb * cB + zh * cH + (EPI == 4 ? kc * kcStride : 0);

    __shared__ __align__(16) ushort_t As[64 * 64];
    __shared__ __align__(16) ushort_t Bs[64 * 64];

    int tid = threadIdx.x, lane = tid & 63, wave = tid >> 6;
    int wm = wave >> 1, wn = wave & 1;
    int m0 = blockIdx.y * 64, n0 = blockIdx.x * 64;
    int srow = lane >> 3;                               // row within 8-row chunk
    int scol = ((lane & 7) ^ srow) * 8;                 // swizzled 16B slot (elems)

    f32x4 acc[2][2];
    #pragma unroll
    for (int i = 0; i < 2; ++i)
        #pragma unroll
        for (int j = 0; j < 2; ++j) acc[i][j] = f32x4{0.f, 0.f, 0.f, 0.f};

    int r = lane & 15, g = lane >> 4, rs = r & 7;

    for (int k0 = 0; k0 < Kchunk; k0 += 64) {
        // stage 64x64 A + 64x64 B: 16 chunks of 8 rows; waves 0,1 -> A, waves 2,3 -> B
        #pragma unroll
        for (int c0 = 0; c0 < 4; ++c0) {
            int c = wave * 4 + c0;
            const ushort_t* src;
            ushort_t* dst;
            if (c < 8) {
                src = A + (long)(m0 + c * 8 + srow) * lda + k0 + scol;
                dst = As + c * 512;
            } else {
                src = B + (long)(n0 + (c - 8) * 8 + srow) * ldb + k0 + scol;
                dst = Bs + (c - 8) * 512;
            }
            __builtin_amdgcn_global_load_lds(
                (const __attribute__((address_space(1))) unsigned int*)src,
                (__attribute__((address_space(3))) unsigned int*)dst, 16, 0, 0);
        }
        __syncthreads();
        bf16x8 af[2][2], bfr[2][2];   // [frag][khalf]
        #pragma unroll
        for (int i = 0; i < 2; ++i) {
            int row = wm * 32 + i * 16 + r;
            #pragma unroll
            for (int kh = 0; kh < 2; ++kh) {
                int sl = (kh * 4 + g) ^ rs;
                af[i][kh] = *(const bf16x8*)((const char*)As + row * 128 + sl * 16);
            }
        }
        #pragma unroll
        for (int j = 0; j < 2; ++j) {
            int row = wn * 32 + j * 16 + r;
            #pragma unroll
            for (int kh = 0; kh < 2; ++kh) {
                int sl = (kh * 4 + g) ^ rs;
                bfr[j][kh] = *(const bf16x8*)((const char*)Bs + row * 128 + sl * 16);
            }
        }
        #pragma unroll
        for (int kh = 0; kh < 2; ++kh)
            #pragma unroll
            for (int i = 0; i < 2; ++i)
                #pragma unroll
                for (int j = 0; j < 2; ++j)
                    acc[i][j] = __builtin_amdgcn_mfma_f32_16x16x32_bf16(af[i][kh], bfr[j][kh], acc[i][j], 0, 0, 0);
        __syncthreads();
    }

    int gr = (lane >> 4) * 4, cL = lane & 15;
    #pragma unroll
    for (int i = 0; i < 2; ++i) {
        int mB = m0 + wm * 32 + i * 16 + gr;
        #pragma unroll
        for (int j = 0; j < 2; ++j) {
            int n = n0 + wn * 32 + j * 16 + cL;
            float bn = 0.f;
            if constexpr (EPI == 0 || EPI == 1) {
                if (biasbase) bn = ((const float*)biasbase)[n];
            }
            #pragma unroll
            for (int rr = 0; rr < 4; ++rr) {
                float vv = acc[i][j][rr];
                long cidx = (long)(mB + rr) * ldc + n;
                if constexpr (EPI == 0) {
                    stC(C, cidx, vv + bn);
                } else if constexpr (EPI == 1) {
                    stC(C, cidx, gelu_tanh(vv + bn));
                } else if constexpr (EPI == 2) {
                    const ushort_t* bp = (const ushort_t*)biasbase + zb * biB + zh * biH;
                    stC(C, cidx, vv * 0.125f + b2f(bp[(long)(mB + rr) * ldbias + n]));
                } else {
                    stC(C, cidx, vv);
                }
            }
        }
    }
}

// ---------------- fused split-K reduce + bias + scaled residual ----------------
// xout[m][n] = xin[m][n] + al[n]/sqrt(1+al^2) * (sum_kc P[kc][m][n] + bias[n])
__global__ __launch_bounds__(256) void k_red_res(const float* __restrict__ P, int kSplit,
        const float* __restrict__ bias, const float* __restrict__ ada, int lw,
        const float* __restrict__ xin, float* __restrict__ xout) {
    int gidx = blockIdx.x * 256 + threadIdx.x;      // 196608 float4's
    int e4 = gidx * 4;
    int m = e4 >> 9, n = e4 & 511;
    int b = (m >= NT);
    const float* al = ada + (long)(lw * 2 + b) * E3 + 1024;
    float4 s = *(const float4*)(P + e4);
    for (int kc = 1; kc < kSplit; ++kc) {
        float4 p = *(const float4*)(P + (long)kc * 786432 + e4);
        s.x += p.x; s.y += p.y; s.z += p.z; s.w += p.w;
    }
    float4 bv = *(const float4*)(bias + n);
    float4 av = *(const float4*)(al + n);
    float4 xv = *(const float4*)(xin + e4);
    float4 r;
    r.x = xv.x + av.x * rsqrtf(1.f + av.x * av.x) * (s.x + bv.x);
    r.y = xv.y + av.y * rsqrtf(1.f + av.y * av.y) * (s.y + bv.y);
    r.z = xv.z + av.z * rsqrtf(1.f + av.z * av.z) * (s.z + bv.z);
    r.w = xv.w + av.w * rsqrtf(1.f + av.w * av.w) * (s.w + bv.w);
    *(float4*)(xout + e4) = r;
}

// ---------------- PV split-K reduce: P[kc][bh][nt][d] -> attnb bf16 [b][nt][h*64+d] ----------------
__global__ __launch_bounds__(256) void k_red_pv(const float* __restrict__ P, ushort_t* __restrict__ attnb) {
    int blk = blockIdx.x;                 // 768 = 16 bh * 48
    int bh = blk / 48, sub = blk % 48;
    int inner = sub * 256 + threadIdx.x;  // 0..12287
    int nt = inner >> 4, d = (inner & 15) * 4;
    long src = (long)bh * 49152 + nt * 64 + d;
    float4 s = *(const float4*)(P + src);
    #pragma unroll
    for (int kc = 1; kc < 4; ++kc) {
        float4 p = *(const float4*)(P + (long)kc * 786432 + src);
        s.x += p.x; s.y += p.y; s.z += p.z; s.w += p.w;
    }
    int b = bh >> 3, h = bh & 7;
    long off = ((long)(b * NT + nt) * EDIM) + h * 64 + d;
    unsigned int p0 = (unsigned int)f2b(s.x) | ((unsigned int)f2b(s.y) << 16);
    unsigned int p1 = (unsigned int)f2b(s.z) | ((unsigned int)f2b(s.w) << 16);
    unsigned int* dst = (unsigned int*)(attnb + off);
    dst[0] = p0; dst[1] = p1;
}

extern "C" void kernel_launch(void* const* d_in, const int* in_sizes, int n_in,
                              void* d_out, int out_size, void* d_ws, size_t ws_size,
                              hipStream_t stream) {
    const float* x       = (const float*)d_in[0];
    const float* t       = (const float*)d_in[1];
    const float* vec_map = (const float*)d_in[2];
    const float* W_rb    = (const float*)d_in[3];
    const float* b_rb    = (const float*)d_in[4];
    const float* W_embed = (const float*)d_in[5];
    const float* b_embed = (const float*)d_in[6];
    const float* pos_emb = (const float*)d_in[7];
    const float* a1W1    = (const float*)d_in[8];
    const float* a1b1    = (const float*)d_in[9];
    const float* a1W2    = (const float*)d_in[10];
    const float* a1b2    = (const float*)d_in[11];
    const float* qkv_W   = (const float*)d_in[12];
    const float* qkv_b   = (const float*)d_in[13];
    const float* out_W   = (const float*)d_in[14];
    const float* out_b   = (const float*)d_in[15];
    const float* a2W1    = (const float*)d_in[16];
    const float* a2b1    = (const float*)d_in[17];
    const float* a2W2    = (const float*)d_in[18];
    const float* a2b2    = (const float*)d_in[19];
    const float* mlp_W1  = (const float*)d_in[20];
    const float* mlp_b1  = (const float*)d_in[21];
    const float* mlp_W2  = (const float*)d_in[22];
    const float* mlp_b2  = (const float*)d_in[23];

    float* ws = (float*)d_ws;
    size_t o = 0;
    float* v        = ws + o; o += 8192;
    ushort_t* biasT = (ushort_t*)(ws + o); o += 4718592;   // 16*768*768 bf16
    float* logits   = ws + o; o += 9437184;                // 16*768*768 f32 (probs overwrite as bf16)
    float* ada      = ws + o; o += 24576;
    float* xc       = ws + o; o += 786432;
    ushort_t* ln16  = (ushort_t*)(ws + o); o += 393216;    // 1536x512
    ushort_t* qkv16 = (ushort_t*)(ws + o); o += 1179648;   // 1536x1536
    ushort_t* vT    = (ushort_t*)(ws + o); o += 393216;    // 16x64x768
    ushort_t* attnb = (ushort_t*)(ws + o); o += 393216;    // 1536x512
    ushort_t* mlph  = (ushort_t*)(ws + o); o += 1572864;   // 1536x2048
    ushort_t* qkvWt = (ushort_t*)(ws + o); o += 1572864;   // 4x1536x512
    ushort_t* outWt = (ushort_t*)(ws + o); o += 524288;    // 4x512x512
    ushort_t* mlp1Wt = (ushort_t*)(ws + o); o += 2097152;  // 4x2048x512
    ushort_t* mlp2Wt = (ushort_t*)(ws + o); o += 2097152;  // 4x512x2048
    float* P_pv     = ws + o; o += 3145728;                // 4*16*768*64 f32
    float* P_proj   = ws + o; o += 3145728;                // 4*1536*512 f32

    k_vnorm<<<6, 256, 0, stream>>>(vec_map, v);
    k_bias<<<TB * NT, 256, 0, stream>>>(v, W_rb, b_rb, biasT);
    k_embed<<<TB * NT, 256, 0, stream>>>(x, W_embed, b_embed, pos_emb, xc);
    k_adaln<<<dim3(16, 6), 256, 0, stream>>>(t, a1W1, a1b1, a1W2, a1b2, a2W1, a2b1, a2W2, a2b2, ada);
    k_wT<<<dim3(24, 8, 4), 256, 0, stream>>>(qkv_W,  qkvWt,  512, 1536);
    k_wT<<<dim3(8,  8, 4), 256, 0, stream>>>(out_W,  outWt,  512, 512);
    k_wT<<<dim3(32, 8, 4), 256, 0, stream>>>(mlp_W1, mlp1Wt, 512, 2048);
    k_wT<<<dim3(8, 32, 4), 256, 0, stream>>>(mlp_W2, mlp2Wt, 2048, 512);

    const long qB = (long)NT * E3, qH = 192;                 // qkv16 strides (ushort)
    const long lB = (long)NH * NT * NT, lH = (long)NT * NT;  // logits f32 / biasT ushort strides
    const long pB = 2 * lB, pH = 2 * lH;                     // probs-as-bf16 strides (ushort)
    const long vB = (long)NH * 64 * NT, vH = (long)64 * NT;  // vT strides (ushort)

    for (int l = 0; l < 4; ++l) {
        int lw0 = l * 2, lw1 = l * 2 + 1;
        // --- attention half ---
        k_lnmod<<<TB * NT, 256, 0, stream>>>(xc, ada, ln16, lw0);
        k_mm64<0, ushort_t><<<dim3(24, 24, 1), 256, 0, stream>>>(
            ln16, qkvWt + (long)l * 786432, qkv_b + l * E3, qkv16,
            512, 1, 512, 512, E3, 0, 0, 0, 0, 0, 0, 0, 0, 0, 0);
        k_vT<<<dim3(12, 16), 256, 0, stream>>>(qkv16, vT);
        k_mm64<2, float><<<dim3(12, 12, 16), 256, 0, stream>>>(
            qkv16, qkv16 + 64, biasT, logits,
            64, 1, E3, E3, NT, NT, qB, qH, qB, qH, lB, lH, lB, lH, 0);
        k_softmax<<<TB * NH * NT, 256, 0, stream>>>(logits);
        k_mm64<4, float><<<dim3(1, 12, 64), 256, 0, stream>>>(
            (const ushort_t*)logits, vT, nullptr, P_pv,
            192, 4, E3, NT, 64, 0, pB, pH, vB, vH, (long)NH * 49152, 49152, 0, 0, 786432);
        k_red_pv<<<768, 256, 0, stream>>>(P_pv, attnb);
        k_mm64<4, float><<<dim3(8, 24, 2), 256, 0, stream>>>(
            attnb, outWt + (long)l * 262144, nullptr, P_proj,
            256, 2, 512, 512, EDIM, 0, 0, 0, 0, 0, 0, 0, 0, 0, 786432);
        k_red_res<<<768, 256, 0, stream>>>(P_proj, 2, out_b + l * EDIM, ada, lw0, xc, xc);
        // --- mlp half ---
        k_lnmod<<<TB * NT, 256, 0, stream>>>(xc, ada, ln16, lw1);
        k_mm64<1, ushort_t><<<dim3(32, 24, 1), 256, 0, stream>>>(
            ln16, mlp1Wt + (long)l * 1048576, mlp_b1 + l * E4, mlph,
            512, 1, 512, 512, E4, 0, 0, 0, 0, 0, 0, 0, 0, 0, 0);
        k_mm64<4, float><<<dim3(8, 24, 4), 256, 0, stream>>>(
            mlph, mlp2Wt + (long)l * 1048576, nullptr, P_proj,
            512, 4, 2048, 2048, EDIM, 0, 0, 0, 0, 0, 0, 0, 0, 0, 786432);
        k_red_res<<<768, 256, 0, stream>>>(P_proj, 4, mlp_b2 + l * EDIM, ada, lw1, xc,
            (l == 3) ? (float*)d_out : xc);
    }
}

// Round 4
// 431.058 us; speedup vs baseline: 3.6244x; 1.2683x over previous
//
#include <hip/hip_runtime.h>
#include <hip/hip_bf16.h>

// HEALPixTransformer: B=2, Nt=768, E=512, H=8, hd=64, T=256, F=64, L=4
// Round 4: k_bias rewritten as register-resident MFMA (pos-feature gen in regs,
// 2x mfma_16x16x32_bf16 per 16 pairs, no LDS matmul traffic). GEMM ladder
// unchanged from round 3 (64x64 tiles, XOR swizzle, split-K + fused epilogues).

#define NT 768
#define EDIM 512
#define E3 1536
#define E4 2048
#define NH 8
#define TB 2

typedef unsigned short ushort_t;
typedef __attribute__((ext_vector_type(8))) short bf16x8;
typedef __attribute__((ext_vector_type(4))) float f32x4;

__device__ inline float b2f(ushort_t u) {
    unsigned int i = ((unsigned int)u) << 16; float f;
    __builtin_memcpy(&f, &i, 4); return f;
}
__device__ inline ushort_t f2b(float f) {
    __hip_bfloat16 h = __float2bfloat16(f);
    ushort_t u; __builtin_memcpy(&u, &h, 2); return u;
}
__device__ inline float gelu_tanh(float u) {
    float z = 1.5957691216057308f * (u + 0.044715f * u * u * u);
    z = fminf(z, 40.f);
    float t = __expf(z);
    float th = (t - 1.f) / (t + 1.f);
    return 0.5f * u * (1.f + th);
}

// ---------------- vnorm ----------------
__global__ __launch_bounds__(256) void k_vnorm(const float* __restrict__ vm, float* __restrict__ v) {
    int idx = blockIdx.x * 256 + threadIdx.x;
    if (idx >= TB * NT) return;
    float s0 = 0.f, s1 = 0.f, s2 = 0.f;
    #pragma unroll
    for (int p = 0; p < 4; ++p) {
        s0 += vm[(idx * 4 + p) * 3 + 0];
        s1 += vm[(idx * 4 + p) * 3 + 1];
        s2 += vm[(idx * 4 + p) * 3 + 2];
    }
    float inv = 1.f / sqrtf(s0 * s0 + s1 * s1 + s2 * s2);
    v[idx * 3 + 0] = s0 * inv; v[idx * 3 + 1] = s1 * inv; v[idx * 3 + 2] = s2 * inv;
}

// ---------------- bias table via MFMA: biasT[b][h][q][k] (bf16) ----------------
// bias(q,k,h) = b_rb[h] + sum_f sin(f*theta)*W_rb[f][h] + cos(f*theta)*W_rb[32+f][h]
// Per 16-pair tile: A[m][kk] (m=pair, kk=feature) built in regs, B = W_rb rows.
__global__ __launch_bounds__(256) void k_bias(const float* __restrict__ v, const float* __restrict__ W_rb,
                                              const float* __restrict__ b_rb, ushort_t* __restrict__ biasT) {
    int bq = blockIdx.x; int b = bq / NT, q = bq % NT;
    __shared__ float sv[NT * 3];
    int tid = threadIdx.x, lane = tid & 63, wave = tid >> 6;
    for (int i = tid; i < NT * 3; i += 256) sv[i] = v[b * NT * 3 + i];

    int g = lane >> 4, col = lane & 15;     // k-group, (A-row | C-col)
    // B fragments (W_rb rows), loaded once: bs[j]=W[8g+j][col], bc[j]=W[32+8g+j][col]
    ushort_t tw[16];
    #pragma unroll
    for (int j = 0; j < 8; ++j) {
        float wsv = (col < 8) ? W_rb[(g * 8 + j) * 8 + col] : 0.f;
        float wcv = (col < 8) ? W_rb[(32 + g * 8 + j) * 8 + col] : 0.f;
        tw[j] = f2b(wsv); tw[8 + j] = f2b(wcv);
    }
    bf16x8 bsf, bcf;
    __builtin_memcpy(&bsf, tw, 16);
    __builtin_memcpy(&bcf, tw + 8, 16);
    float brh = (col < 8) ? b_rb[col] : 0.f;
    __syncthreads();

    float vq0 = sv[q * 3], vq1 = sv[q * 3 + 1], vq2 = sv[q * 3 + 2];
    float gf = (float)(8 * g);

    for (int it = 0; it < 12; ++it) {
        int tile = (it * 4 + wave) * 16;
        int p = tile + col;                 // pair whose theta this lane generates
        float d0 = vq0 - sv[p * 3], d1 = vq1 - sv[p * 3 + 1], d2 = vq2 - sv[p * 3 + 2];
        float dot = 1.f - 0.5f * (d0 * d0 + d1 * d1 + d2 * d2);
        dot = fminf(1.f, fmaxf(-1.f, dot));
        float theta = acosf(dot) * (2000.f / 31.f);
        float s1, c1; __sincosf(theta, &s1, &c1);
        float sg, cg; __sincosf(theta * gf, &sg, &cg);
        ushort_t fs[16];
        #pragma unroll
        for (int j = 0; j < 8; ++j) {
            fs[j] = f2b(sg); fs[8 + j] = f2b(cg);
            float ns = sg * c1 + cg * s1;
            cg = cg * c1 - sg * s1;
            sg = ns;
        }
        bf16x8 asf, acf;
        __builtin_memcpy(&asf, fs, 16);
        __builtin_memcpy(&acf, fs + 8, 16);
        f32x4 acc = {0.f, 0.f, 0.f, 0.f};
        acc = __builtin_amdgcn_mfma_f32_16x16x32_bf16(asf, bsf, acc, 0, 0, 0);
        acc = __builtin_amdgcn_mfma_f32_16x16x32_bf16(acf, bcf, acc, 0, 0, 0);
        // C[row][col]: row = 4g + r (pair within tile), col = head
        if (col < 8) {
            ushort_t o[4];
            #pragma unroll
            for (int r = 0; r < 4; ++r) o[r] = f2b(acc[r] + brh);
            long off = (long)(b * 8 + col) * NT * NT + (long)q * NT + tile + 4 * g;
            uint2 pk;
            pk.x = (unsigned int)o[0] | ((unsigned int)o[1] << 16);
            pk.y = (unsigned int)o[2] | ((unsigned int)o[3] << 16);
            *(uint2*)(biasT + off) = pk;
        }
    }
}

// ---------------- embed ----------------
__global__ __launch_bounds__(256) void k_embed(const float* __restrict__ x, const float* __restrict__ W,
                                               const float* __restrict__ be, const float* __restrict__ pe,
                                               float* __restrict__ xc) {
    int row = blockIdx.x; int nt = row % NT;
    __shared__ float sx[16];
    int tid = threadIdx.x;
    if (tid < 16) sx[tid] = x[row * 16 + tid];
    __syncthreads();
    for (int e = tid; e < EDIM; e += 256) {
        float a = be[e] + pe[nt * EDIM + e];
        #pragma unroll
        for (int j = 0; j < 16; ++j) a += sx[j] * W[j * EDIM + e];
        xc[(long)row * EDIM + e] = a;
    }
}

// ---------------- adaLN precompute ----------------
__global__ __launch_bounds__(256) void k_adaln(const float* __restrict__ t,
    const float* __restrict__ a1W1, const float* __restrict__ a1b1, const float* __restrict__ a1W2, const float* __restrict__ a1b2,
    const float* __restrict__ a2W1, const float* __restrict__ a2b1, const float* __restrict__ a2W2, const float* __restrict__ a2b2,
    float* __restrict__ ada) {
    int blk = blockIdx.x; int b = blk & 1, lw = blk >> 1; int which = lw & 1, l = lw >> 1;
    const float* W1 = (which ? a2W1 : a1W1) + (long)l * 256 * 256;
    const float* b1 = (which ? a2b1 : a1b1) + l * 256;
    const float* W2 = (which ? a2W2 : a1W2) + (long)l * 256 * E3;
    const float* b2 = (which ? a2b2 : a1b2) + l * E3;
    __shared__ float st[256], sh[256];
    int tid = threadIdx.x;
    st[tid] = t[b * 256 + tid];
    __syncthreads();
    float a = b1[tid];
    for (int i = 0; i < 256; ++i) a += st[i] * W1[i * 256 + tid];
    sh[tid] = a / (1.f + __expf(-a));
    __syncthreads();
    int c = blockIdx.y * 256 + tid;
    float m = b2[c];
    for (int i = 0; i < 256; ++i) m += sh[i] * W2[i * E3 + c];
    ada[(long)(lw * 2 + b) * E3 + c] = m;
}

// ---------------- LN + modulate (bf16 out) ----------------
__global__ __launch_bounds__(256) void k_lnmod(const float* __restrict__ xc, const float* __restrict__ ada,
                                               ushort_t* __restrict__ out, int lw) {
    int row = blockIdx.x; int b = row / NT;
    const float* ap = ada + (long)(lw * 2 + b) * E3;
    int tid = threadIdx.x;
    float2 vv = *(const float2*)(xc + (long)row * EDIM + tid * 2);
    float s1 = vv.x + vv.y, s2 = vv.x * vv.x + vv.y * vv.y;
    for (int o = 32; o; o >>= 1) { s1 += __shfl_down(s1, o); s2 += __shfl_down(s2, o); }
    __shared__ float sr[8];
    if ((tid & 63) == 0) { sr[tid >> 6] = s1; sr[4 + (tid >> 6)] = s2; }
    __syncthreads();
    s1 = sr[0] + sr[1] + sr[2] + sr[3];
    s2 = sr[4] + sr[5] + sr[6] + sr[7];
    float mu = s1 * (1.f / 512.f);
    float var = s2 * (1.f / 512.f) - mu * mu;
    float inv = rsqrtf(var + 1e-6f);
    int e = tid * 2;
    float r0 = (ap[e] + 1.f) * ((vv.x - mu) * inv) + ap[512 + e];
    float r1 = (ap[e + 1] + 1.f) * ((vv.y - mu) * inv) + ap[512 + e + 1];
    unsigned int pk = (unsigned int)f2b(r0) | ((unsigned int)f2b(r1) << 16);
    ((unsigned int*)out)[(long)row * 256 + tid] = pk;
}

// ---------------- softmax: fp32 row -> bf16 row in place ----------------
__global__ __launch_bounds__(256) void k_softmax(float* __restrict__ logits) {
    float* p = logits + (long)blockIdx.x * NT;
    ushort_t* pb = (ushort_t*)p;
    int tid = threadIdx.x;
    float v0 = p[tid], v1 = p[tid + 256], v2 = p[tid + 512];
    float mx = fmaxf(v0, fmaxf(v1, v2));
    for (int o = 32; o; o >>= 1) mx = fmaxf(mx, __shfl_down(mx, o));
    __shared__ float sr[8];
    if ((tid & 63) == 0) sr[tid >> 6] = mx;
    __syncthreads();
    mx = fmaxf(fmaxf(sr[0], sr[1]), fmaxf(sr[2], sr[3]));
    float e0 = __expf(v0 - mx), e1 = __expf(v1 - mx), e2 = __expf(v2 - mx);
    float s = e0 + e1 + e2;
    for (int o = 32; o; o >>= 1) s += __shfl_down(s, o);
    if ((tid & 63) == 0) sr[4 + (tid >> 6)] = s;
    __syncthreads();
    s = sr[4] + sr[5] + sr[6] + sr[7];
    float inv = 1.f / s;
    pb[tid] = f2b(e0 * inv); pb[tid + 256] = f2b(e1 * inv); pb[tid + 512] = f2b(e2 * inv);
}

// ---------------- weight convert+transpose: W[K][N] fp32 -> Wt[N][K] bf16 ----------------
__global__ __launch_bounds__(256) void k_wT(const float* __restrict__ W, ushort_t* __restrict__ Wt,
                                            int Kd, int Nd) {
    const float* Wp = W + (long)blockIdx.z * Kd * Nd;
    ushort_t* Wtp = Wt + (long)blockIdx.z * Kd * Nd;
    int n0 = blockIdx.x * 64, k0 = blockIdx.y * 64;
    __shared__ float s[64][65];
    int tid = threadIdx.x;
    #pragma unroll
    for (int it = 0; it < 4; ++it) {
        int idx = tid + it * 256;
        int r = idx >> 4, c4 = (idx & 15) * 4;
        float4 vv = *(const float4*)(Wp + (long)(k0 + r) * Nd + n0 + c4);
        s[r][c4] = vv.x; s[r][c4 + 1] = vv.y; s[r][c4 + 2] = vv.z; s[r][c4 + 3] = vv.w;
    }
    __syncthreads();
    #pragma unroll
    for (int it = 0; it < 4; ++it) {
        int idx = tid + it * 256;
        int rn = idx >> 4, ck = (idx & 15) * 4;
        long base = (long)(n0 + rn) * Kd + k0 + ck;
        #pragma unroll
        for (int j = 0; j < 4; ++j) Wtp[base + j] = f2b(s[ck + j][rn]);
    }
}

// ---------------- v transpose: qkv[b][nt][h*192+128+d] -> vT[bh][d][nt] ----------------
__global__ __launch_bounds__(256) void k_vT(const ushort_t* __restrict__ qkv16, ushort_t* __restrict__ vT) {
    int bh = blockIdx.y; int b = bh >> 3, h = bh & 7;
    int nt0 = blockIdx.x * 64;
    __shared__ ushort_t s[64][80];
    int tid = threadIdx.x;
    #pragma unroll
    for (int it = 0; it < 2; ++it) {
        int idx = tid + it * 256;
        int rnt = idx >> 3, c8 = (idx & 7) * 8;
        bf16x8 vv = *(const bf16x8*)(qkv16 + ((long)(b * NT + nt0 + rnt) * E3 + h * 192 + 128 + c8));
        *(bf16x8*)&s[rnt][c8] = vv;
    }
    __syncthreads();
    #pragma unroll
    for (int it = 0; it < 2; ++it) {
        int idx = tid + it * 256;
        int d = idx >> 3, n8 = (idx & 7) * 8;
        ushort_t tmp[8];
        #pragma unroll
        for (int j = 0; j < 8; ++j) tmp[j] = s[n8 + j][d];
        bf16x8 ov; __builtin_memcpy(&ov, tmp, 16);
        *(bf16x8*)(vT + ((long)bh * 64 + d) * NT + nt0 + n8) = ov;
    }
}

// ---------------- MFMA GEMM, 64x64 tile, K-step 64, XOR swizzle, split-K ----------------
__device__ inline void stC(float* C, long i, float v) { C[i] = v; }
__device__ inline void stC(ushort_t* C, long i, float v) { C[i] = f2b(v); }

template<int EPI, typename CT>
__global__ __launch_bounds__(256) void k_mm64(
        const ushort_t* __restrict__ A0, const ushort_t* __restrict__ B0,
        const void* __restrict__ biasbase, CT* __restrict__ C0,
        int Kchunk, int kSplit, int lda, int ldb, int ldc, int ldbias,
        long aB, long aH, long bB, long bH, long cB, long cH, long biB, long biH, long kcStride) {
    int z = blockIdx.z;
    int batch = z / kSplit, kc = z - batch * kSplit;
    int zb = batch >> 3, zh = batch & 7;
    const ushort_t* A = A0 + zb * aB + zh * aH + (long)kc * Kchunk;
    const ushort_t* B = B0 + zb * bB + zh * bH + (long)kc * Kchunk;
    CT* C = C0 + zb * cB + zh * cH + (EPI == 4 ? kc * kcStride : 0);

    __shared__ __align__(16) ushort_t As[64 * 64];
    __shared__ __align__(16) ushort_t Bs[64 * 64];

    int tid = threadIdx.x, lane = tid & 63, wave = tid >> 6;
    int wm = wave >> 1, wn = wave & 1;
    int m0 = blockIdx.y * 64, n0 = blockIdx.x * 64;
    int srow = lane >> 3;
    int scol = ((lane & 7) ^ srow) * 8;

    f32x4 acc[2][2];
    #pragma unroll
    for (int i = 0; i < 2; ++i)
        #pragma unroll
        for (int j = 0; j < 2; ++j) acc[i][j] = f32x4{0.f, 0.f, 0.f, 0.f};

    int r = lane & 15, g = lane >> 4, rs = r & 7;

    for (int k0 = 0; k0 < Kchunk; k0 += 64) {
        #pragma unroll
        for (int c0 = 0; c0 < 4; ++c0) {
            int c = wave * 4 + c0;
            const ushort_t* src;
            ushort_t* dst;
            if (c < 8) {
                src = A + (long)(m0 + c * 8 + srow) * lda + k0 + scol;
                dst = As + c * 512;
            } else {
                src = B + (long)(n0 + (c - 8) * 8 + srow) * ldb + k0 + scol;
                dst = Bs + (c - 8) * 512;
            }
            __builtin_amdgcn_global_load_lds(
                (const __attribute__((address_space(1))) unsigned int*)src,
                (__attribute__((address_space(3))) unsigned int*)dst, 16, 0, 0);
        }
        __syncthreads();
        bf16x8 af[2][2], bfr[2][2];
        #pragma unroll
        for (int i = 0; i < 2; ++i) {
            int row = wm * 32 + i * 16 + r;
            #pragma unroll
            for (int kh = 0; kh < 2; ++kh) {
                int sl = (kh * 4 + g) ^ rs;
                af[i][kh] = *(const bf16x8*)((const char*)As + row * 128 + sl * 16);
            }
        }
        #pragma unroll
        for (int j = 0; j < 2; ++j) {
            int row = wn * 32 + j * 16 + r;
            #pragma unroll
            for (int kh = 0; kh < 2; ++kh) {
                int sl = (kh * 4 + g) ^ rs;
                bfr[j][kh] = *(const bf16x8*)((const char*)Bs + row * 128 + sl * 16);
            }
        }
        #pragma unroll
        for (int kh = 0; kh < 2; ++kh)
            #pragma unroll
            for (int i = 0; i < 2; ++i)
                #pragma unroll
                for (int j = 0; j < 2; ++j)
                    acc[i][j] = __builtin_amdgcn_mfma_f32_16x16x32_bf16(af[i][kh], bfr[j][kh], acc[i][j], 0, 0, 0);
        __syncthreads();
    }

    int gr = (lane >> 4) * 4, cL = lane & 15;
    #pragma unroll
    for (int i = 0; i < 2; ++i) {
        int mB = m0 + wm * 32 + i * 16 + gr;
        #pragma unroll
        for (int j = 0; j < 2; ++j) {
            int n = n0 + wn * 32 + j * 16 + cL;
            float bn = 0.f;
            if constexpr (EPI == 0 || EPI == 1) {
                if (biasbase) bn = ((const float*)biasbase)[n];
            }
            #pragma unroll
            for (int rr = 0; rr < 4; ++rr) {
                float vv = acc[i][j][rr];
                long cidx = (long)(mB + rr) * ldc + n;
                if constexpr (EPI == 0) {
                    stC(C, cidx, vv + bn);
                } else if constexpr (EPI == 1) {
                    stC(C, cidx, gelu_tanh(vv + bn));
                } else if constexpr (EPI == 2) {
                    const ushort_t* bp = (const ushort_t*)biasbase + zb * biB + zh * biH;
                    stC(C, cidx, vv * 0.125f + b2f(bp[(long)(mB + rr) * ldbias + n]));
                } else {
                    stC(C, cidx, vv);
                }
            }
        }
    }
}

// ---------------- fused split-K reduce + bias + scaled residual ----------------
__global__ __launch_bounds__(256) void k_red_res(const float* __restrict__ P, int kSplit,
        const float* __restrict__ bias, const float* __restrict__ ada, int lw,
        const float* __restrict__ xin, float* __restrict__ xout) {
    int gidx = blockIdx.x * 256 + threadIdx.x;
    int e4 = gidx * 4;
    int m = e4 >> 9, n = e4 & 511;
    int b = (m >= NT);
    const float* al = ada + (long)(lw * 2 + b) * E3 + 1024;
    float4 s = *(const float4*)(P + e4);
    for (int kc = 1; kc < kSplit; ++kc) {
        float4 p = *(const float4*)(P + (long)kc * 786432 + e4);
        s.x += p.x; s.y += p.y; s.z += p.z; s.w += p.w;
    }
    float4 bv = *(const float4*)(bias + n);
    float4 av = *(const float4*)(al + n);
    float4 xv = *(const float4*)(xin + e4);
    float4 r;
    r.x = xv.x + av.x * rsqrtf(1.f + av.x * av.x) * (s.x + bv.x);
    r.y = xv.y + av.y * rsqrtf(1.f + av.y * av.y) * (s.y + bv.y);
    r.z = xv.z + av.z * rsqrtf(1.f + av.z * av.z) * (s.z + bv.z);
    r.w = xv.w + av.w * rsqrtf(1.f + av.w * av.w) * (s.w + bv.w);
    *(float4*)(xout + e4) = r;
}

// ---------------- PV split-K reduce ----------------
__global__ __launch_bounds__(256) void k_red_pv(const float* __restrict__ P, ushort_t* __restrict__ attnb) {
    int blk = blockIdx.x;
    int bh = blk / 48, sub = blk % 48;
    int inner = sub * 256 + threadIdx.x;
    int nt = inner >> 4, d = (inner & 15) * 4;
    long src = (long)bh * 49152 + nt * 64 + d;
    float4 s = *(const float4*)(P + src);
    #pragma unroll
    for (int kc = 1; kc < 4; ++kc) {
        float4 p = *(const float4*)(P + (long)kc * 786432 + src);
        s.x += p.x; s.y += p.y; s.z += p.z; s.w += p.w;
    }
    int b = bh >> 3, h = bh & 7;
    long off = ((long)(b * NT + nt) * EDIM) + h * 64 + d;
    unsigned int p0 = (unsigned int)f2b(s.x) | ((unsigned int)f2b(s.y) << 16);
    unsigned int p1 = (unsigned int)f2b(s.z) | ((unsigned int)f2b(s.w) << 16);
    unsigned int* dst = (unsigned int*)(attnb + off);
    dst[0] = p0; dst[1] = p1;
}

extern "C" void kernel_launch(void* const* d_in, const int* in_sizes, int n_in,
                              void* d_out, int out_size, void* d_ws, size_t ws_size,
                              hipStream_t stream) {
    const float* x       = (const float*)d_in[0];
    const float* t       = (const float*)d_in[1];
    const float* vec_map = (const float*)d_in[2];
    const float* W_rb    = (const float*)d_in[3];
    const float* b_rb    = (const float*)d_in[4];
    const float* W_embed = (const float*)d_in[5];
    const float* b_embed = (const float*)d_in[6];
    const float* pos_emb = (const float*)d_in[7];
    const float* a1W1    = (const float*)d_in[8];
    const float* a1b1    = (const float*)d_in[9];
    const float* a1W2    = (const float*)d_in[10];
    const float* a1b2    = (const float*)d_in[11];
    const float* qkv_W   = (const float*)d_in[12];
    const float* qkv_b   = (const float*)d_in[13];
    const float* out_W   = (const float*)d_in[14];
    const float* out_b   = (const float*)d_in[15];
    const float* a2W1    = (const float*)d_in[16];
    const float* a2b1    = (const float*)d_in[17];
    const float* a2W2    = (const float*)d_in[18];
    const float* a2b2    = (const float*)d_in[19];
    const float* mlp_W1  = (const float*)d_in[20];
    const float* mlp_b1  = (const float*)d_in[21];
    const float* mlp_W2  = (const float*)d_in[22];
    const float* mlp_b2  = (const float*)d_in[23];

    float* ws = (float*)d_ws;
    size_t o = 0;
    float* v        = ws + o; o += 8192;
    ushort_t* biasT = (ushort_t*)(ws + o); o += 4718592;
    float* logits   = ws + o; o += 9437184;
    float* ada      = ws + o; o += 24576;
    float* xc       = ws + o; o += 786432;
    ushort_t* ln16  = (ushort_t*)(ws + o); o += 393216;
    ushort_t* qkv16 = (ushort_t*)(ws + o); o += 1179648;
    ushort_t* vT    = (ushort_t*)(ws + o); o += 393216;
    ushort_t* attnb = (ushort_t*)(ws + o); o += 393216;
    ushort_t* mlph  = (ushort_t*)(ws + o); o += 1572864;
    ushort_t* qkvWt = (ushort_t*)(ws + o); o += 1572864;
    ushort_t* outWt = (ushort_t*)(ws + o); o += 524288;
    ushort_t* mlp1Wt = (ushort_t*)(ws + o); o += 2097152;
    ushort_t* mlp2Wt = (ushort_t*)(ws + o); o += 2097152;
    float* P_pv     = ws + o; o += 3145728;
    float* P_proj   = ws + o; o += 3145728;

    k_vnorm<<<6, 256, 0, stream>>>(vec_map, v);
    k_bias<<<TB * NT, 256, 0, stream>>>(v, W_rb, b_rb, biasT);
    k_embed<<<TB * NT, 256, 0, stream>>>(x, W_embed, b_embed, pos_emb, xc);
    k_adaln<<<dim3(16, 6), 256, 0, stream>>>(t, a1W1, a1b1, a1W2, a1b2, a2W1, a2b1, a2W2, a2b2, ada);
    k_wT<<<dim3(24, 8, 4), 256, 0, stream>>>(qkv_W,  qkvWt,  512, 1536);
    k_wT<<<dim3(8,  8, 4), 256, 0, stream>>>(out_W,  outWt,  512, 512);
    k_wT<<<dim3(32, 8, 4), 256, 0, stream>>>(mlp_W1, mlp1Wt, 512, 2048);
    k_wT<<<dim3(8, 32, 4), 256, 0, stream>>>(mlp_W2, mlp2Wt, 2048, 512);

    const long qB = (long)NT * E3, qH = 192;
    const long lB = (long)NH * NT * NT, lH = (long)NT * NT;
    const long pB = 2 * lB, pH = 2 * lH;
    const long vB = (long)NH * 64 * NT, vH = (long)64 * NT;

    for (int l = 0; l < 4; ++l) {
        int lw0 = l * 2, lw1 = l * 2 + 1;
        // --- attention half ---
        k_lnmod<<<TB * NT, 256, 0, stream>>>(xc, ada, ln16, lw0);
        k_mm64<0, ushort_t><<<dim3(24, 24, 1), 256, 0, stream>>>(
            ln16, qkvWt + (long)l * 786432, qkv_b + l * E3, qkv16,
            512, 1, 512, 512, E3, 0, 0, 0, 0, 0, 0, 0, 0, 0, 0);
        k_vT<<<dim3(12, 16), 256, 0, stream>>>(qkv16, vT);
        k_mm64<2, float><<<dim3(12, 12, 16), 256, 0, stream>>>(
            qkv16, qkv16 + 64, biasT, logits,
            64, 1, E3, E3, NT, NT, qB, qH, qB, qH, lB, lH, lB, lH, 0);
        k_softmax<<<TB * NH * NT, 256, 0, stream>>>(logits);
        k_mm64<4, float><<<dim3(1, 12, 64), 256, 0, stream>>>(
            (const ushort_t*)logits, vT, nullptr, P_pv,
            192, 4, E3, NT, 64, 0, pB, pH, vB, vH, (long)NH * 49152, 49152, 0, 0, 786432);
        k_red_pv<<<768, 256, 0, stream>>>(P_pv, attnb);
        k_mm64<4, float><<<dim3(8, 24, 2), 256, 0, stream>>>(
            attnb, outWt + (long)l * 262144, nullptr, P_proj,
            256, 2, 512, 512, EDIM, 0, 0, 0, 0, 0, 0, 0, 0, 0, 786432);
        k_red_res<<<768, 256, 0, stream>>>(P_proj, 2, out_b + l * EDIM, ada, lw0, xc, xc);
        // --- mlp half ---
        k_lnmod<<<TB * NT, 256, 0, stream>>>(xc, ada, ln16, lw1);
        k_mm64<1, ushort_t><<<dim3(32, 24, 1), 256, 0, stream>>>(
            ln16, mlp1Wt + (long)l * 1048576, mlp_b1 + l * E4, mlph,
            512, 1, 512, 512, E4, 0, 0, 0, 0, 0, 0, 0, 0, 0, 0);
        k_mm64<4, float><<<dim3(8, 24, 4), 256, 0, stream>>>(
            mlph, mlp2Wt + (long)l * 1048576, nullptr, P_proj,
            512, 4, 2048, 2048, EDIM, 0, 0, 0, 0, 0, 0, 0, 0, 0, 786432);
        k_red_res<<<768, 256, 0, stream>>>(P_proj, 4, mlp_b2 + l * EDIM, ada, lw1, xc,
            (l == 3) ? (float*)d_out : xc);
    }
}